// Round 5
// baseline (235.567 us; speedup 1.0000x reference)
//
#include <hip/hip_runtime.h>

// LIF forward: X [B, T, N] fp32 -> spikes [B, T, N] fp32
// B=128, T=32, N=8192.
//   mem = mem + (x - mem)/2 ; spike = (mem-1 > 0) ; mem = spike ? 0 : mem
// Memory-bound. WRITE_SIZE=134 MB exact; FETCH_SIZE=65.6 MB (input is
// half-L3-resident across harness iterations) -> HBM floor < 42 us.
// Harness dur_us includes two 512 MiB poison fills (~80 us each).
// R1: float4 naive, VGPR=24..36, 85.5 us (loads sunk / array scratched).
// R3: float2 full-occupancy TLP -> ~72 us, 2.9 TB/s.
// R5: asm 32x dwordx2 burst + vmcnt(0) + asm stores: ~63 us. PASS.
// R6: + chunked counted waits: NEUTRAL -> intra-wave schedule irrelevant.
// R7/R8: asm stores FAIL: VMEM store-data hazard (compiler reuses the
//     store-data VGPRs while the store is in flight). Asm stores retired.
// R9: x[16] f32x4 array + asm loads + plain stores: PASS but 84.5 us,
//     VGPR_Count=36 (!). DIAGNOSIS: 16 live quads need >=64 VGPRs -- 36 is
//     impossible -> compiler demoted x[] to SCRATCH (same signature as
//     R4). Each load is serialized by its spill-wait + a dependent
//     scratch round-trip + ~268 MB scratch traffic. Pressure estimate
//     near the launch_bounds(256,4) 128-VGPR cap made the allocator
//     demote the aggregate (rule-#20 failure mode).
// R10 (this): NAMED REGISTERS, depth 8. Eight named f32x4 SSA values
//     (x0..x7) can never be scratch-demoted. 4 phases of {8 asm dwordx4
//     loads -> vmcnt(0) drain -> re-tie -> plain compute + plain stores}.
//     ~32 data VGPRs + overhead ~= 60-70 total, far under the cap.
//     In-flight 8 KB/wave x 16 waves/CU = 128 KB/CU >> ~9 KB Little's-law
//     need at 900 cy HBM latency. Depth granularity proven neutral (R6).
//     Expect VGPR ~64 (the fix signature), kernel ~50-60 us.

typedef float f32x4 __attribute__((ext_vector_type(4)));

#define T_STEPS 32
#define N4 2048           // N/4 float4 elements per (b,t) row
#define TN4 (T_STEPS * N4)

__global__ __launch_bounds__(256, 4) void lif_fwd_kernel(
    const f32x4* __restrict__ X, f32x4* __restrict__ out)
{
    const int idx = blockIdx.x * blockDim.x + threadIdx.x;  // over B * N4
    const int b = idx >> 11;          // / N4
    const int n = idx & (N4 - 1);
    const size_t base = (size_t)b * (size_t)TN4 + (size_t)n;

    const f32x4* p = X + base;
    f32x4* __restrict__ po = out + base;

    float m0 = 0.f, m1 = 0.f, m2 = 0.f, m3 = 0.f;

    // Named SSA values -- cannot be demoted to scratch.
    f32x4 x0, x1, x2, x3, x4, x5, x6, x7;

    // Force-issue one dwordx4 load (volatile asm: program-order pinned,
    // cannot be sunk by IR passes).
#define LOADV(v) do {                                                       \
        asm volatile("global_load_dwordx4 %0, %1, off"                      \
                     : "=&v"(v) : "v"(p));                                  \
        p += N4;                                                            \
    } while (0)

    // Re-tie after the drain so compute cannot be hoisted above it.
#define RETIE(v) asm volatile("" : "+v"(v))

    // One timestep: exact reference order. Plain store (compiler-managed
    // store-data hazards -- the R8 lesson).
#define STEPV(v) do {                                                       \
        m0 = m0 + ((v).x - m0) * 0.5f;                                      \
        m1 = m1 + ((v).y - m1) * 0.5f;                                      \
        m2 = m2 + ((v).z - m2) * 0.5f;                                      \
        m3 = m3 + ((v).w - m3) * 0.5f;                                      \
        f32x4 s;                                                            \
        s.x = (m0 - 1.0f > 0.0f) ? 1.0f : 0.0f;                             \
        s.y = (m1 - 1.0f > 0.0f) ? 1.0f : 0.0f;                             \
        s.z = (m2 - 1.0f > 0.0f) ? 1.0f : 0.0f;                             \
        s.w = (m3 - 1.0f > 0.0f) ? 1.0f : 0.0f;                             \
        m0 = (s.x != 0.0f) ? 0.0f : m0;                                     \
        m1 = (s.y != 0.0f) ? 0.0f : m1;                                     \
        m2 = (s.z != 0.0f) ? 0.0f : m2;                                     \
        m3 = (s.w != 0.0f) ? 0.0f : m3;                                     \
        *po = s;                                                            \
        po += N4;                                                           \
    } while (0)

#pragma unroll
    for (int phase = 0; phase < 4; ++phase) {
        // ---- burst-issue 8 timestep loads (8 KB/wave in flight) ----
        LOADV(x0); LOADV(x1); LOADV(x2); LOADV(x3);
        LOADV(x4); LOADV(x5); LOADV(x6); LOADV(x7);

        // Drain. "memory" clobber also keeps prior plain stores ordered
        // (conservative, safe; store retire hides under the load drain).
        asm volatile("s_waitcnt vmcnt(0)" ::: "memory");

        RETIE(x0); RETIE(x1); RETIE(x2); RETIE(x3);
        RETIE(x4); RETIE(x5); RETIE(x6); RETIE(x7);

        // ---- scan 8 timesteps + plain stores ----
        STEPV(x0); STEPV(x1); STEPV(x2); STEPV(x3);
        STEPV(x4); STEPV(x5); STEPV(x6); STEPV(x7);
    }

#undef LOADV
#undef RETIE
#undef STEPV
}

extern "C" void kernel_launch(void* const* d_in, const int* in_sizes, int n_in,
                              void* d_out, int out_size, void* d_ws, size_t ws_size,
                              hipStream_t stream) {
    const f32x4* X = (const f32x4*)d_in[0];
    f32x4* out = (f32x4*)d_out;

    const int total = in_sizes[0];          // B*T*N = 33554432 elements
    const int B = total / (T_STEPS * 8192); // 128
    const int nthreads = B * N4;            // 262144

    const int block = 256;
    const int grid = (nthreads + block - 1) / block;  // 1024 = 4 blocks/CU

    lif_fwd_kernel<<<grid, block, 0, stream>>>(X, out);
}

// Round 6
// 227.503 us; speedup vs baseline: 1.0354x; 1.0354x over previous
//
#include <hip/hip_runtime.h>

// LIF forward: X [B, T, N] fp32 -> spikes [B, T, N] fp32
// B=128, T=32, N=8192.
//   mem = mem + (x - mem)/2 ; spike = (mem-1 > 0) ; mem = spike ? 0 : mem
// Memory-bound. WRITE_SIZE=134 MB exact; FETCH_SIZE=65.6 MB (input half
// L3-resident across harness iters) -> HBM floor ~31-40 us. Harness dur
// includes two 512 MiB poison fills (~82 us each, ~165 us fixed).
// R1: float4 naive loop, VGPR=24, 85.5 us (loads sunk to uses).
// R3: float2 plain loop, full occupancy: 72 us.
// R5/R6: asm 32x dwordx2 burst + vmcnt + ASM stores: ~59-63 us. PASS but
//     asm stores are a store-data-hazard minefield (R8: absmax 3.2).
// R7/R8: asm stores FAIL (VMEM store-data hazard). Retired.
// R9: f32x4 x[16] array + asm loads + plain stores: 84.5 us, VGPR=36 ->
//     array demoted to scratch, loads serialized.
// R10: f32x4 NAMED x0..x7 + asm loads + plain stores: 84 us, VGPR=24 --
//     physically impossible for 8 live quads -> allocator serialized the
//     burst anyway (spill through L2; FETCH/WRITE unchanged). EVERY
//     float4 variant (R1/R9/R10) collapses to ~84-85 us regardless of
//     structure. Lesson: inline-asm loads + compiler allocation is a
//     losing fight; the allocator silently destroys intended liveness.
// R11 (this): ZERO ASM. Single basic block: fully-unrolled straight-line
//     32 plain float2 loads into 32 named scalars, then 32 compute+store
//     steps. __launch_bounds__(256,2) raises the per-wave VGPR budget to
//     256 so the pre-RA scheduler has NO pressure reason to sink the
//     loads (the R1/R4 sinking was a high-occupancy register-target
//     artifact, loop-structured). __restrict__ makes loads/store
//     non-aliasing so the load pack can stay hoisted. Expected: compiler
//     emits the R5 shape (load burst, waitcnt, compute+stores) with its
//     own correct hazard handling.
//     Occupancy 8 waves/CU x 16 KB in flight = 128 KB/CU >> 22 KB
//     Little's-law need at ~900 cy HBM latency.
//     FALSIFIABLE SIGNATURE: VGPR_Count ~80-120 = loads hoisted (expect
//     ~50-62 us). VGPR <= 40 = loads sunk, theory dead -> revert to R6.

#define T_STEPS 32
#define N2 4096           // N/2 float2 elements per (b,t) row
#define TN2 (T_STEPS * N2)

__global__ __launch_bounds__(256, 2) void lif_fwd_kernel(
    const float2* __restrict__ X, float2* __restrict__ out)
{
    const int idx = blockIdx.x * blockDim.x + threadIdx.x;  // over B * N2
    const int b = idx >> 12;          // / N2
    const int n = idx & (N2 - 1);
    const size_t base = (size_t)b * (size_t)TN2 + (size_t)n;

    const float2* __restrict__ p = X + base;
    float2* __restrict__ po = out + base;

    // ---- 32 plain loads, straight-line, named scalars (no array, no
    // loop, no asm). One basic block: the scheduler owns the order and
    // with a 256-VGPR budget has no reason to sink these. ----
#define LD(i) const float2 x##i = p[(size_t)(i) * (size_t)N2]
    LD(0);  LD(1);  LD(2);  LD(3);  LD(4);  LD(5);  LD(6);  LD(7);
    LD(8);  LD(9);  LD(10); LD(11); LD(12); LD(13); LD(14); LD(15);
    LD(16); LD(17); LD(18); LD(19); LD(20); LD(21); LD(22); LD(23);
    LD(24); LD(25); LD(26); LD(27); LD(28); LD(29); LD(30); LD(31);
#undef LD

    float m0 = 0.f, m1 = 0.f;

    // ---- 32 scan steps + plain stores (compiler-managed hazards). ----
#define STEP(i) do {                                                        \
        m0 = m0 + (x##i.x - m0) * 0.5f;                                     \
        m1 = m1 + (x##i.y - m1) * 0.5f;                                     \
        float2 s;                                                           \
        s.x = (m0 - 1.0f > 0.0f) ? 1.0f : 0.0f;                             \
        s.y = (m1 - 1.0f > 0.0f) ? 1.0f : 0.0f;                             \
        m0 = (s.x != 0.0f) ? 0.0f : m0;                                     \
        m1 = (s.y != 0.0f) ? 0.0f : m1;                                     \
        po[(size_t)(i) * (size_t)N2] = s;                                   \
    } while (0)
    STEP(0);  STEP(1);  STEP(2);  STEP(3);  STEP(4);  STEP(5);  STEP(6);  STEP(7);
    STEP(8);  STEP(9);  STEP(10); STEP(11); STEP(12); STEP(13); STEP(14); STEP(15);
    STEP(16); STEP(17); STEP(18); STEP(19); STEP(20); STEP(21); STEP(22); STEP(23);
    STEP(24); STEP(25); STEP(26); STEP(27); STEP(28); STEP(29); STEP(30); STEP(31);
#undef STEP
}

extern "C" void kernel_launch(void* const* d_in, const int* in_sizes, int n_in,
                              void* d_out, int out_size, void* d_ws, size_t ws_size,
                              hipStream_t stream) {
    const float2* X = (const float2*)d_in[0];
    float2* out = (float2*)d_out;

    const int total = in_sizes[0];          // B*T*N = 33554432 elements
    const int B = total / (T_STEPS * 8192); // 128
    const int nthreads = B * N2;            // 524288

    const int block = 256;
    const int grid = (nthreads + block - 1) / block;  // 2048

    lif_fwd_kernel<<<grid, block, 0, stream>>>(X, out);
}